// Round 2
// baseline (241.281 us; speedup 1.0000x reference)
//
#include <hip/hip_runtime.h>
#include <stdint.h>

typedef __attribute__((ext_vector_type(8))) short short8;
typedef __attribute__((ext_vector_type(4))) float float4v;
typedef __attribute__((ext_vector_type(4))) unsigned short ushort4v;

#define Bq 2
#define Sq 2048
#define Dq 1024
#define Hq 16
#define HDq 64

__device__ __forceinline__ unsigned short f2bf(float f) {
  union { float f; uint32_t u; } v; v.f = f;
  uint32_t r = (v.u + 0x7FFFu + ((v.u >> 16) & 1u)) >> 16;
  return (unsigned short)r;
}

__global__ __launch_bounds__(256) void cvt_kernel(const float* __restrict__ src,
                                                  unsigned short* __restrict__ dst, int n4) {
  int i = blockIdx.x * 256 + threadIdx.x;
  if (i >= n4) return;
  float4v f = ((const float4v*)src)[i];
  ushort4v o;
#pragma unroll
  for (int j = 0; j < 4; j++) o[j] = f2bf(f[j]);
  ((ushort4v*)dst)[i] = o;
}

// C = A(bf16 MxK) @ W^T (W is NxK bf16, row n = output col n). 128x128 tile, BK=32.
// OUTPROJ: fp32 out + bias, row-major (M x 1024). Else: bf16 out scattered to (b,H,s,hd).
template <bool OUTPROJ>
__global__ __launch_bounds__(256) void gemm_bt_kernel(
    const unsigned short* __restrict__ A,
    const unsigned short* __restrict__ W0,
    const unsigned short* __restrict__ W1,
    const unsigned short* __restrict__ W2,
    unsigned short* __restrict__ q_dst,
    unsigned short* __restrict__ k_dst,
    unsigned short* __restrict__ v_dst,
    float* __restrict__ f_dst,
    const float* __restrict__ bias) {
  constexpr int K = 1024;
  const int z = blockIdx.z;
  const unsigned short* W = (z == 0) ? W0 : (z == 1) ? W1 : W2;
  unsigned short* qkv = (z == 0) ? q_dst : (z == 1) ? k_dst : v_dst;

  __shared__ unsigned short Asm[128 * 32];
  __shared__ unsigned short Bsm[128 * 32];

  const int t = threadIdx.x;
  const int wave = t >> 6, lane = t & 63;
  const int quad = lane >> 4, l16 = lane & 15;
  const int wy = wave >> 1, wx = wave & 1;
  const int row0 = blockIdx.x * 128;
  const int col0 = blockIdx.y * 128;

  float4v zero = {0.f, 0.f, 0.f, 0.f};
  float4v acc[4][4];
#pragma unroll
  for (int i = 0; i < 4; i++)
#pragma unroll
    for (int j = 0; j < 4; j++) acc[i][j] = zero;

  const int sr = t >> 2;
  const int sc = (t & 3) << 3;
  const unsigned short* ga = A + (size_t)(row0 + sr) * K + sc;
  const unsigned short* gb = W + (size_t)(col0 + sr) * K + sc;

  for (int k0 = 0; k0 < K; k0 += 32) {
    short8 a0 = *(const short8*)(ga + k0);
    short8 a1 = *(const short8*)(ga + (size_t)64 * K + k0);
    short8 b0 = *(const short8*)(gb + k0);
    short8 b1 = *(const short8*)(gb + (size_t)64 * K + k0);
    *(short8*)(&Asm[sr * 32 + sc]) = a0;
    *(short8*)(&Asm[(sr + 64) * 32 + sc]) = a1;
    *(short8*)(&Bsm[sr * 32 + sc]) = b0;
    *(short8*)(&Bsm[(sr + 64) * 32 + sc]) = b1;
    __syncthreads();
    short8 af[4], bf[4];
#pragma unroll
    for (int mb = 0; mb < 4; mb++)
      af[mb] = *(const short8*)(&Asm[(wy * 64 + mb * 16 + l16) * 32 + quad * 8]);
#pragma unroll
    for (int nb = 0; nb < 4; nb++)
      bf[nb] = *(const short8*)(&Bsm[(wx * 64 + nb * 16 + l16) * 32 + quad * 8]);
#pragma unroll
    for (int mb = 0; mb < 4; mb++)
#pragma unroll
      for (int nb = 0; nb < 4; nb++)
        acc[mb][nb] = __builtin_amdgcn_mfma_f32_16x16x32_bf16(af[mb], bf[nb], acc[mb][nb], 0, 0, 0);
    __syncthreads();
  }

#pragma unroll
  for (int mb = 0; mb < 4; mb++) {
#pragma unroll
    for (int nb = 0; nb < 4; nb++) {
#pragma unroll
      for (int r = 0; r < 4; r++) {
        int row = row0 + wy * 64 + mb * 16 + quad * 4 + r;  // token index
        int o = col0 + wx * 64 + nb * 16 + l16;             // output feature
        float val = acc[mb][nb][r];
        if (OUTPROJ) {
          f_dst[(size_t)row * 1024 + o] = val + bias[o];
        } else {
          int b = row >> 11, s = row & 2047;
          int h = o >> 6, hd = o & 63;
          qkv[(size_t)((b * Hq + h) * Sq + s) * HDq + hd] = f2bf(val);
        }
      }
    }
  }
}

// Flash-style attention, unmasked softmax without max-subtraction (logits bounded).
// Block: 256 thr (4 waves), 128 q-rows (32/wave), key tiles of 64.
__global__ __launch_bounds__(256) void attn_kernel(
    const unsigned short* __restrict__ Q,
    const unsigned short* __restrict__ Kg,
    const unsigned short* __restrict__ Vg,
    unsigned short* __restrict__ ctx) {
  const int bh = blockIdx.y;
  const int q0 = blockIdx.x * 128;
  const int t = threadIdx.x;
  const int wave = t >> 6, lane = t & 63;
  const int quad = lane >> 4, l16 = lane & 15;

  __shared__ unsigned short Ksm[64 * 64];      // [key][hd]
  __shared__ unsigned short Vsm[64 * 80];      // [hd][key], padded to 80 for banks
  __shared__ unsigned short Psm[4][32 * 64];   // per-wave [qrow][key]

  const unsigned short* Qb = Q + (size_t)bh * Sq * HDq;
  const unsigned short* Kb = Kg + (size_t)bh * Sq * HDq;
  const unsigned short* Vb = Vg + (size_t)bh * Sq * HDq;

  short8 qf[2][2];
#pragma unroll
  for (int rb = 0; rb < 2; rb++)
#pragma unroll
    for (int ks = 0; ks < 2; ks++)
      qf[rb][ks] = *(const short8*)(Qb + (size_t)(q0 + wave * 32 + rb * 16 + l16) * HDq + ks * 32 + quad * 8);

  float4v zero = {0.f, 0.f, 0.f, 0.f};
  float4v of[2][4];
  float lpart[2][4];
#pragma unroll
  for (int rb = 0; rb < 2; rb++) {
#pragma unroll
    for (int hb = 0; hb < 4; hb++) of[rb][hb] = zero;
#pragma unroll
    for (int r = 0; r < 4; r++) lpart[rb][r] = 0.f;
  }

  for (int kt = 0; kt < Sq; kt += 64) {
    // stage K naturally, V transposed
#pragma unroll
    for (int i = 0; i < 2; i++) {
      int c = t + i * 256;
      int kr = c >> 3, kc = (c & 7) << 3;
      short8 kv = *(const short8*)(Kb + (size_t)(kt + kr) * HDq + kc);
      *(short8*)(&Ksm[kr * 64 + kc]) = kv;
      int vr = c & 63, vc = (c >> 6) << 3;
      short8 vv = *(const short8*)(Vb + (size_t)(kt + vr) * HDq + vc);
#pragma unroll
      for (int j = 0; j < 8; j++) Vsm[(vc + j) * 80 + vr] = (unsigned short)vv[j];
    }
    __syncthreads();

    // S = Q @ K^T (per wave: 32 q x 64 keys)
    float4v sf[2][4];
#pragma unroll
    for (int rb = 0; rb < 2; rb++)
#pragma unroll
      for (int cb = 0; cb < 4; cb++) sf[rb][cb] = zero;
#pragma unroll
    for (int cb = 0; cb < 4; cb++) {
#pragma unroll
      for (int ks = 0; ks < 2; ks++) {
        short8 kf = *(const short8*)(&Ksm[(cb * 16 + l16) * 64 + ks * 32 + quad * 8]);
#pragma unroll
        for (int rb = 0; rb < 2; rb++)
          sf[rb][cb] = __builtin_amdgcn_mfma_f32_16x16x32_bf16(qf[rb][ks], kf, sf[rb][cb], 0, 0, 0);
      }
    }

    // P = exp(S/8); accumulate row-sums; write P to per-wave LDS (C-layout -> A-layout)
#pragma unroll
    for (int rb = 0; rb < 2; rb++)
#pragma unroll
      for (int cb = 0; cb < 4; cb++)
#pragma unroll
        for (int r = 0; r < 4; r++) {
          float p = __expf(sf[rb][cb][r] * 0.125f);
          lpart[rb][r] += p;
          Psm[wave][(rb * 16 + quad * 4 + r) * 64 + cb * 16 + l16] = f2bf(p);
        }
    __syncthreads();

    // O += P @ V
#pragma unroll
    for (int ks = 0; ks < 2; ks++) {
      short8 vf[4];
#pragma unroll
      for (int hb = 0; hb < 4; hb++)
        vf[hb] = *(const short8*)(&Vsm[(hb * 16 + l16) * 80 + ks * 32 + quad * 8]);
#pragma unroll
      for (int rb = 0; rb < 2; rb++) {
        short8 pf = *(const short8*)(&Psm[wave][(rb * 16 + l16) * 64 + ks * 32 + quad * 8]);
#pragma unroll
        for (int hb = 0; hb < 4; hb++)
          of[rb][hb] = __builtin_amdgcn_mfma_f32_16x16x32_bf16(pf, vf[hb], of[rb][hb], 0, 0, 0);
      }
    }
    __syncthreads();
  }

  // reduce softmax denominators across the 16 column-lanes, then write ctx
#pragma unroll
  for (int rb = 0; rb < 2; rb++)
#pragma unroll
    for (int r = 0; r < 4; r++) {
      float l = lpart[rb][r];
      l += __shfl_xor(l, 1, 64);
      l += __shfl_xor(l, 2, 64);
      l += __shfl_xor(l, 4, 64);
      l += __shfl_xor(l, 8, 64);
      lpart[rb][r] = 1.0f / l;
    }

  const int b = bh >> 4, h = bh & 15;
#pragma unroll
  for (int rb = 0; rb < 2; rb++)
#pragma unroll
    for (int hb = 0; hb < 4; hb++)
#pragma unroll
      for (int r = 0; r < 4; r++) {
        int srow = q0 + wave * 32 + rb * 16 + quad * 4 + r;
        int d = h * 64 + hb * 16 + l16;
        ctx[(size_t)(b * Sq + srow) * Dq + d] = f2bf(of[rb][hb][r] * lpart[rb][r]);
      }
}

extern "C" void kernel_launch(void* const* d_in, const int* in_sizes, int n_in,
                              void* d_out, int out_size, void* d_ws, size_t ws_size,
                              hipStream_t stream) {
  (void)in_sizes; (void)n_in; (void)out_size; (void)ws_size;
  const float* x  = (const float*)d_in[0];
  const float* wq = (const float*)d_in[1];
  const float* wk = (const float*)d_in[2];
  const float* wv = (const float*)d_in[3];
  const float* wo = (const float*)d_in[4];
  const float* bo = (const float*)d_in[5];
  float* out = (float*)d_out;

  char* ws = (char*)d_ws;
  const size_t MB = 1u << 20;
  unsigned short* xb  = (unsigned short*)(ws + 0 * MB);   // 8 MB  (4096x1024 bf16)
  unsigned short* wqb = (unsigned short*)(ws + 8 * MB);   // 2 MB
  unsigned short* wkb = (unsigned short*)(ws + 10 * MB);  // 2 MB
  unsigned short* wvb = (unsigned short*)(ws + 12 * MB);  // 2 MB
  unsigned short* wob = (unsigned short*)(ws + 14 * MB);  // 2 MB
  unsigned short* qb  = (unsigned short*)(ws + 16 * MB);  // 8 MB  (B,H,S,HD)
  unsigned short* kb  = (unsigned short*)(ws + 24 * MB);  // 8 MB
  unsigned short* vb  = (unsigned short*)(ws + 32 * MB);  // 8 MB
  unsigned short* cxb = (unsigned short*)(ws + 40 * MB);  // 8 MB  (B,S,D)

  cvt_kernel<<<4096, 256, 0, stream>>>(x, xb, (Bq * Sq * Dq) / 4);
  cvt_kernel<<<1024, 256, 0, stream>>>(wq, wqb, (Dq * Dq) / 4);
  cvt_kernel<<<1024, 256, 0, stream>>>(wk, wkb, (Dq * Dq) / 4);
  cvt_kernel<<<1024, 256, 0, stream>>>(wv, wvb, (Dq * Dq) / 4);
  cvt_kernel<<<1024, 256, 0, stream>>>(wo, wob, (Dq * Dq) / 4);

  gemm_bt_kernel<false><<<dim3(32, 8, 3), 256, 0, stream>>>(
      xb, wqb, wkb, wvb, qb, kb, vb, nullptr, nullptr);
  attn_kernel<<<dim3(16, 32), 256, 0, stream>>>(qb, kb, vb, cxb);
  gemm_bt_kernel<true><<<dim3(32, 8, 1), 256, 0, stream>>>(
      cxb, wob, wob, wob, nullptr, nullptr, nullptr, out, bo);
}

// Round 3
// 226.028 us; speedup vs baseline: 1.0675x; 1.0675x over previous
//
#include <hip/hip_runtime.h>
#include <stdint.h>

typedef __attribute__((ext_vector_type(8))) short short8;
typedef __attribute__((ext_vector_type(4))) float float4v;
typedef __attribute__((ext_vector_type(4))) unsigned short ushort4v;

#define Bq 2
#define Sq 2048
#define Dq 1024
#define Hq 16
#define HDq 64

__device__ __forceinline__ unsigned short f2bf(float f) {
  union { float f; uint32_t u; } v; v.f = f;
  uint32_t r = (v.u + 0x7FFFu + ((v.u >> 16) & 1u)) >> 16;
  return (unsigned short)r;
}

__global__ __launch_bounds__(256) void cvt_kernel(const float* __restrict__ src,
                                                  unsigned short* __restrict__ dst, int n4) {
  int i = blockIdx.x * 256 + threadIdx.x;
  if (i >= n4) return;
  float4v f = ((const float4v*)src)[i];
  ushort4v o;
#pragma unroll
  for (int j = 0; j < 4; j++) o[j] = f2bf(f[j]);
  ((ushort4v*)dst)[i] = o;
}

// all 4 weights (each 1024x1024) in one launch; dst regions contiguous, 1M elems apart
__global__ __launch_bounds__(256) void cvtw_kernel(const float* __restrict__ w0,
                                                   const float* __restrict__ w1,
                                                   const float* __restrict__ w2,
                                                   const float* __restrict__ w3,
                                                   unsigned short* __restrict__ dst) {
  const int z = blockIdx.y;
  const float* src = (z == 0) ? w0 : (z == 1) ? w1 : (z == 2) ? w2 : w3;
  int i = blockIdx.x * 256 + threadIdx.x;
  float4v f = ((const float4v*)src)[i];
  ushort4v o;
#pragma unroll
  for (int j = 0; j < 4; j++) o[j] = f2bf(f[j]);
  ((ushort4v*)(dst + (size_t)z * 1048576))[i] = o;
}

// C = A(bf16 MxK) @ W^T. 128x128 tile, BK=32. LDS stride padded 32->36 shorts
// (unpadded: all 16 lanes of a quad read the same 4 banks on b128 frag reads).
template <bool OUTPROJ>
__global__ __launch_bounds__(256) void gemm_bt_kernel(
    const unsigned short* __restrict__ A,
    const unsigned short* __restrict__ W0,
    const unsigned short* __restrict__ W1,
    const unsigned short* __restrict__ W2,
    unsigned short* __restrict__ q_dst,
    unsigned short* __restrict__ k_dst,
    unsigned short* __restrict__ v_dst,
    float* __restrict__ f_dst,
    const float* __restrict__ bias) {
  constexpr int K = 1024;
  constexpr int LSTR = 36;  // padded LDS stride in shorts
  const int z = blockIdx.z;
  const unsigned short* W = (z == 0) ? W0 : (z == 1) ? W1 : W2;
  unsigned short* qkv = (z == 0) ? q_dst : (z == 1) ? k_dst : v_dst;

  __shared__ unsigned short Asm[128 * LSTR];
  __shared__ unsigned short Bsm[128 * LSTR];

  const int t = threadIdx.x;
  const int wave = t >> 6, lane = t & 63;
  const int quad = lane >> 4, l16 = lane & 15;
  const int wy = wave >> 1, wx = wave & 1;
  const int row0 = blockIdx.x * 128;
  const int col0 = blockIdx.y * 128;

  float4v zero = {0.f, 0.f, 0.f, 0.f};
  float4v acc[4][4];
#pragma unroll
  for (int i = 0; i < 4; i++)
#pragma unroll
    for (int j = 0; j < 4; j++) acc[i][j] = zero;

  const int sr = t >> 2;
  const int sc = (t & 3) << 3;
  const unsigned short* ga = A + (size_t)(row0 + sr) * K + sc;
  const unsigned short* gb = W + (size_t)(col0 + sr) * K + sc;

  for (int k0 = 0; k0 < K; k0 += 32) {
    short8 a0 = *(const short8*)(ga + k0);
    short8 a1 = *(const short8*)(ga + (size_t)64 * K + k0);
    short8 b0 = *(const short8*)(gb + k0);
    short8 b1 = *(const short8*)(gb + (size_t)64 * K + k0);
    *(short8*)(&Asm[sr * LSTR + sc]) = a0;
    *(short8*)(&Asm[(sr + 64) * LSTR + sc]) = a1;
    *(short8*)(&Bsm[sr * LSTR + sc]) = b0;
    *(short8*)(&Bsm[(sr + 64) * LSTR + sc]) = b1;
    __syncthreads();
    short8 af[4], bf[4];
#pragma unroll
    for (int mb = 0; mb < 4; mb++)
      af[mb] = *(const short8*)(&Asm[(wy * 64 + mb * 16 + l16) * LSTR + quad * 8]);
#pragma unroll
    for (int nb = 0; nb < 4; nb++)
      bf[nb] = *(const short8*)(&Bsm[(wx * 64 + nb * 16 + l16) * LSTR + quad * 8]);
#pragma unroll
    for (int mb = 0; mb < 4; mb++)
#pragma unroll
      for (int nb = 0; nb < 4; nb++)
        acc[mb][nb] = __builtin_amdgcn_mfma_f32_16x16x32_bf16(af[mb], bf[nb], acc[mb][nb], 0, 0, 0);
    __syncthreads();
  }

#pragma unroll
  for (int mb = 0; mb < 4; mb++) {
#pragma unroll
    for (int nb = 0; nb < 4; nb++) {
#pragma unroll
      for (int r = 0; r < 4; r++) {
        int row = row0 + wy * 64 + mb * 16 + quad * 4 + r;  // token index
        int o = col0 + wx * 64 + nb * 16 + l16;             // output feature
        float val = acc[mb][nb][r];
        if (OUTPROJ) {
          f_dst[(size_t)row * 1024 + o] = val + bias[o];
        } else {
          int b = row >> 11, s = row & 2047;
          int h = o >> 6, hd = o & 63;
          qkv[(size_t)((b * Hq + h) * Sq + s) * HDq + hd] = f2bf(val);
        }
      }
    }
  }
}

// Flash-style attention, unmasked softmax without max-subtraction (logits bounded).
// Block: 256 thr (4 waves), 64 q-rows (16/wave), key tiles of 64. Grid 32x32=1024
// blocks -> 4 blocks/CU. Padded LDS strides; 2 barriers/tile (P round-trip is
// per-wave so needs no barrier).
__global__ __launch_bounds__(256) void attn_kernel(
    const unsigned short* __restrict__ Q,
    const unsigned short* __restrict__ Kg,
    const unsigned short* __restrict__ Vg,
    unsigned short* __restrict__ ctx) {
  constexpr int KSTR = 68;  // Ksm/Psm stride (shorts)
  constexpr int VSTR = 72;  // Vsm stride (shorts)
  const int bh = blockIdx.y;
  const int q0 = blockIdx.x * 64;
  const int t = threadIdx.x;
  const int wave = t >> 6, lane = t & 63;
  const int quad = lane >> 4, l16 = lane & 15;

  __shared__ unsigned short Ksm[64 * KSTR];     // [key][hd]
  __shared__ unsigned short Vsm[64 * VSTR];     // [hd][key]
  __shared__ unsigned short Psm[4][16 * KSTR];  // per-wave [qrow][key]

  const unsigned short* Qb = Q + (size_t)bh * Sq * HDq;
  const unsigned short* Kb = Kg + (size_t)bh * Sq * HDq;
  const unsigned short* Vb = Vg + (size_t)bh * Sq * HDq;

  short8 qf[2];
#pragma unroll
  for (int ks = 0; ks < 2; ks++)
    qf[ks] = *(const short8*)(Qb + (size_t)(q0 + wave * 16 + l16) * HDq + ks * 32 + quad * 8);

  float4v zero = {0.f, 0.f, 0.f, 0.f};
  float4v of[4];
  float lpart[4];
#pragma unroll
  for (int hb = 0; hb < 4; hb++) of[hb] = zero;
#pragma unroll
  for (int r = 0; r < 4; r++) lpart[r] = 0.f;

  // V staging: each thread handles 2 adjacent keys x 8 hd, packs key-pairs -> b32
  const int vr2 = (t & 31) * 2;
  const int vc = (t >> 5) << 3;

  for (int kt = 0; kt < Sq; kt += 64) {
    // stage K naturally (b128), V transposed (pack-2 b32)
#pragma unroll
    for (int i = 0; i < 2; i++) {
      int c = t + i * 256;
      int kr = c >> 3, kc = (c & 7) << 3;
      short8 kv = *(const short8*)(Kb + (size_t)(kt + kr) * HDq + kc);
      *(short8*)(&Ksm[kr * KSTR + kc]) = kv;
    }
    {
      short8 v0 = *(const short8*)(Vb + (size_t)(kt + vr2) * HDq + vc);
      short8 v1 = *(const short8*)(Vb + (size_t)(kt + vr2 + 1) * HDq + vc);
#pragma unroll
      for (int j = 0; j < 8; j++) {
        uint32_t pk = (uint32_t)(unsigned short)v0[j] | ((uint32_t)(unsigned short)v1[j] << 16);
        *(uint32_t*)(&Vsm[(vc + j) * VSTR + vr2]) = pk;
      }
    }
    __syncthreads();

    // S = Q @ K^T (per wave: 16 q x 64 keys)
    float4v sf[4];
#pragma unroll
    for (int cb = 0; cb < 4; cb++) sf[cb] = zero;
#pragma unroll
    for (int cb = 0; cb < 4; cb++) {
#pragma unroll
      for (int ks = 0; ks < 2; ks++) {
        short8 kf = *(const short8*)(&Ksm[(cb * 16 + l16) * KSTR + ks * 32 + quad * 8]);
        sf[cb] = __builtin_amdgcn_mfma_f32_16x16x32_bf16(qf[ks], kf, sf[cb], 0, 0, 0);
      }
    }

    // P = exp(S/8); row-sums; write P to per-wave LDS (C-layout -> A-layout).
    // Psm is wave-private: no barrier needed before PV reads (in-wave LDS order).
#pragma unroll
    for (int cb = 0; cb < 4; cb++)
#pragma unroll
      for (int r = 0; r < 4; r++) {
        float p = __expf(sf[cb][r] * 0.125f);
        lpart[r] += p;
        Psm[wave][(quad * 4 + r) * KSTR + cb * 16 + l16] = f2bf(p);
      }

    // O += P @ V
#pragma unroll
    for (int ks = 0; ks < 2; ks++) {
      short8 pf = *(const short8*)(&Psm[wave][l16 * KSTR + ks * 32 + quad * 8]);
#pragma unroll
      for (int hb = 0; hb < 4; hb++) {
        short8 vf = *(const short8*)(&Vsm[(hb * 16 + l16) * VSTR + ks * 32 + quad * 8]);
        of[hb] = __builtin_amdgcn_mfma_f32_16x16x32_bf16(pf, vf, of[hb], 0, 0, 0);
      }
    }
    __syncthreads();
  }

  // reduce softmax denominators across the 16 column-lanes, then write ctx
#pragma unroll
  for (int r = 0; r < 4; r++) {
    float l = lpart[r];
    l += __shfl_xor(l, 1, 64);
    l += __shfl_xor(l, 2, 64);
    l += __shfl_xor(l, 4, 64);
    l += __shfl_xor(l, 8, 64);
    lpart[r] = 1.0f / l;
  }

  const int b = bh >> 4, h = bh & 15;
#pragma unroll
  for (int hb = 0; hb < 4; hb++)
#pragma unroll
    for (int r = 0; r < 4; r++) {
      int srow = q0 + wave * 16 + quad * 4 + r;
      int d = h * 64 + hb * 16 + l16;
      ctx[(size_t)(b * Sq + srow) * Dq + d] = f2bf(of[hb][r] * lpart[r]);
    }
}

extern "C" void kernel_launch(void* const* d_in, const int* in_sizes, int n_in,
                              void* d_out, int out_size, void* d_ws, size_t ws_size,
                              hipStream_t stream) {
  (void)in_sizes; (void)n_in; (void)out_size; (void)ws_size;
  const float* x  = (const float*)d_in[0];
  const float* wq = (const float*)d_in[1];
  const float* wk = (const float*)d_in[2];
  const float* wv = (const float*)d_in[3];
  const float* wo = (const float*)d_in[4];
  const float* bo = (const float*)d_in[5];
  float* out = (float*)d_out;

  char* ws = (char*)d_ws;
  const size_t MB = 1u << 20;
  unsigned short* xb  = (unsigned short*)(ws + 0 * MB);   // 8 MB  (4096x1024 bf16)
  unsigned short* wqb = (unsigned short*)(ws + 8 * MB);   // 2 MB (wq/wk/wv/wo contiguous)
  unsigned short* wkb = (unsigned short*)(ws + 10 * MB);
  unsigned short* wvb = (unsigned short*)(ws + 12 * MB);
  unsigned short* wob = (unsigned short*)(ws + 14 * MB);
  unsigned short* qb  = (unsigned short*)(ws + 16 * MB);  // 8 MB  (B,H,S,HD)
  unsigned short* kb  = (unsigned short*)(ws + 24 * MB);  // 8 MB
  unsigned short* vb  = (unsigned short*)(ws + 32 * MB);  // 8 MB
  unsigned short* cxb = (unsigned short*)(ws + 40 * MB);  // 8 MB  (B,S,D)

  cvt_kernel<<<4096, 256, 0, stream>>>(x, xb, (Bq * Sq * Dq) / 4);
  cvtw_kernel<<<dim3(1024, 4), 256, 0, stream>>>(wq, wk, wv, wo, wqb);

  gemm_bt_kernel<false><<<dim3(32, 8, 3), 256, 0, stream>>>(
      xb, wqb, wkb, wvb, qb, kb, vb, nullptr, nullptr);
  attn_kernel<<<dim3(32, 32), 256, 0, stream>>>(qb, kb, vb, cxb);
  gemm_bt_kernel<true><<<dim3(32, 8, 1), 256, 0, stream>>>(
      cxb, wob, wob, wob, nullptr, nullptr, nullptr, out, bo);
}

// Round 4
// 212.682 us; speedup vs baseline: 1.1345x; 1.0628x over previous
//
#include <hip/hip_runtime.h>
#include <stdint.h>

typedef __attribute__((ext_vector_type(8))) short short8;
typedef __attribute__((ext_vector_type(4))) short short4v;
typedef __attribute__((ext_vector_type(4))) float float4v;
typedef __attribute__((ext_vector_type(4))) unsigned short ushort4v;

#define Bq 2
#define Sq 2048
#define Dq 1024
#define Hq 16
#define HDq 64

__device__ __forceinline__ unsigned short f2bf(float f) {
  union { float f; uint32_t u; } v; v.f = f;
  uint32_t r = (v.u + 0x7FFFu + ((v.u >> 16) & 1u)) >> 16;
  return (unsigned short)r;
}

// async global->LDS, 16B per lane; LDS dest must be wave-uniform base + lane*16.
__device__ __forceinline__ void gl_lds16(const unsigned short* g, unsigned short* l) {
  __builtin_amdgcn_global_load_lds(
      (const __attribute__((address_space(1))) void*)g,
      (__attribute__((address_space(3))) void*)l, 16, 0, 0);
}

__global__ __launch_bounds__(256) void cvt_kernel(const float* __restrict__ src,
                                                  unsigned short* __restrict__ dst, int n4) {
  int i = blockIdx.x * 256 + threadIdx.x;
  if (i >= n4) return;
  float4v f = ((const float4v*)src)[i];
  ushort4v o;
#pragma unroll
  for (int j = 0; j < 4; j++) o[j] = f2bf(f[j]);
  ((ushort4v*)dst)[i] = o;
}

__global__ __launch_bounds__(256) void cvtw_kernel(const float* __restrict__ w0,
                                                   const float* __restrict__ w1,
                                                   const float* __restrict__ w2,
                                                   const float* __restrict__ w3,
                                                   unsigned short* __restrict__ dst) {
  const int z = blockIdx.y;
  const float* src = (z == 0) ? w0 : (z == 1) ? w1 : (z == 2) ? w2 : w3;
  int i = blockIdx.x * 256 + threadIdx.x;
  float4v f = ((const float4v*)src)[i];
  ushort4v o;
#pragma unroll
  for (int j = 0; j < 4; j++) o[j] = f2bf(f[j]);
  ((ushort4v*)(dst + (size_t)z * 1048576))[i] = o;
}

// C = A(bf16 MxK) @ W^T. 128x128 tile, BK=32, m97-style global_load_lds staging.
// LSTR=32 unpadded (required: lds dest = wave base + lane*16B); b128 frag reads
// at 64B row stride are bank-uniform (16B granules cover all 32 banks).
template <bool OUTPROJ>
__global__ __launch_bounds__(256) void gemm_bt_kernel(
    const unsigned short* __restrict__ A,
    const unsigned short* __restrict__ W0,
    const unsigned short* __restrict__ W1,
    const unsigned short* __restrict__ W2,
    unsigned short* __restrict__ q_dst,
    unsigned short* __restrict__ k_dst,
    unsigned short* __restrict__ v_dst,
    float* __restrict__ f_dst,
    const float* __restrict__ bias) {
  constexpr int K = 1024;
  const int z = blockIdx.z;
  const unsigned short* W = (z == 0) ? W0 : (z == 1) ? W1 : W2;
  unsigned short* qkv = (z == 0) ? q_dst : (z == 1) ? k_dst : v_dst;

  __shared__ unsigned short Asm[128 * 32];
  __shared__ unsigned short Bsm[128 * 32];

  const int t = threadIdx.x;
  const int wave = t >> 6, lane = t & 63;
  const int quad = lane >> 4, l16 = lane & 15;
  const int wy = wave >> 1, wx = wave & 1;
  const int row0 = blockIdx.x * 128;
  const int col0 = blockIdx.y * 128;

  float4v zero = {0.f, 0.f, 0.f, 0.f};
  float4v acc[4][4];
#pragma unroll
  for (int i = 0; i < 4; i++)
#pragma unroll
    for (int j = 0; j < 4; j++) acc[i][j] = zero;

  const int sr = t >> 2;
  const int sc = (t & 3) << 3;
  const unsigned short* ga = A + (size_t)(row0 + sr) * K + sc;
  const unsigned short* gb = W + (size_t)(col0 + sr) * K + sc;
  unsigned short* lA0 = &Asm[t * 8];         // == Asm[sr*32 + sc]
  unsigned short* lA1 = &Asm[2048 + t * 8];  // rows 64..127
  unsigned short* lB0 = &Bsm[t * 8];
  unsigned short* lB1 = &Bsm[2048 + t * 8];

  for (int k0 = 0; k0 < K; k0 += 32) {
    gl_lds16(ga + k0, lA0);
    gl_lds16(ga + (size_t)64 * K + k0, lA1);
    gl_lds16(gb + k0, lB0);
    gl_lds16(gb + (size_t)64 * K + k0, lB1);
    __syncthreads();
    short8 af[4], bf[4];
#pragma unroll
    for (int mb = 0; mb < 4; mb++)
      af[mb] = *(const short8*)(&Asm[(wy * 64 + mb * 16 + l16) * 32 + quad * 8]);
#pragma unroll
    for (int nb = 0; nb < 4; nb++)
      bf[nb] = *(const short8*)(&Bsm[(wx * 64 + nb * 16 + l16) * 32 + quad * 8]);
#pragma unroll
    for (int mb = 0; mb < 4; mb++)
#pragma unroll
      for (int nb = 0; nb < 4; nb++)
        acc[mb][nb] = __builtin_amdgcn_mfma_f32_16x16x32_bf16(af[mb], bf[nb], acc[mb][nb], 0, 0, 0);
    __syncthreads();
  }

#pragma unroll
  for (int mb = 0; mb < 4; mb++) {
#pragma unroll
    for (int nb = 0; nb < 4; nb++) {
#pragma unroll
      for (int r = 0; r < 4; r++) {
        int row = row0 + wy * 64 + mb * 16 + quad * 4 + r;  // token index
        int o = col0 + wx * 64 + nb * 16 + l16;             // output feature
        float val = acc[mb][nb][r];
        if (OUTPROJ) {
          f_dst[(size_t)row * 1024 + o] = val + bias[o];
        } else {
          int b = row >> 11, s = row & 2047;
          int h = o >> 6, hd = o & 63;
          qkv[(size_t)((b * Hq + h) * Sq + s) * HDq + hd] = f2bf(val);
        }
      }
    }
  }
}

// Flash-style attention. Computes S^T via mfma(K,Q) so the P fragment for PV is
// built IN-REGISTER from the S^T C-layout (lane: q=l16, keys=quad*4+r; two 16-key
// C-subtiles pack into one K=32 A-frag). No P LDS round-trip. 4 waves x 32 q-rows
// = 128 q/block; 64-key tiles; grid 16x32 = 512 blocks (2/CU).
__global__ __launch_bounds__(256) void attn_kernel(
    const unsigned short* __restrict__ Q,
    const unsigned short* __restrict__ Kg,
    const unsigned short* __restrict__ Vg,
    unsigned short* __restrict__ ctx) {
  constexpr int KSTR = 68;  // Ksm stride (shorts)
  constexpr int VSTR = 72;  // Vsm stride (shorts)
  const int bh = blockIdx.y;
  const int q0 = blockIdx.x * 128;
  const int t = threadIdx.x;
  const int wave = t >> 6, lane = t & 63;
  const int quad = lane >> 4, l16 = lane & 15;

  __shared__ unsigned short Ksm[64 * KSTR];  // [key][hd]
  __shared__ unsigned short Vsm[64 * VSTR];  // [hd][key]

  const unsigned short* Qb = Q + (size_t)bh * Sq * HDq;
  const unsigned short* Kb = Kg + (size_t)bh * Sq * HDq;
  const unsigned short* Vb = Vg + (size_t)bh * Sq * HDq;

  short8 qf[2][2];  // [rb][ks]
#pragma unroll
  for (int rb = 0; rb < 2; rb++)
#pragma unroll
    for (int ks = 0; ks < 2; ks++)
      qf[rb][ks] = *(const short8*)(Qb + (size_t)(q0 + wave * 32 + rb * 16 + l16) * HDq + ks * 32 + quad * 8);

  float4v zero = {0.f, 0.f, 0.f, 0.f};
  float4v of[2][4];
  float lsum[2] = {0.f, 0.f};
#pragma unroll
  for (int rb = 0; rb < 2; rb++)
#pragma unroll
    for (int hb = 0; hb < 4; hb++) of[rb][hb] = zero;

  const int vr2 = (t & 31) * 2;
  const int vc = (t >> 5) << 3;

  for (int kt = 0; kt < Sq; kt += 64) {
    // stage K naturally (b128), V transposed (pack-2 b32)
#pragma unroll
    for (int i = 0; i < 2; i++) {
      int c = t + i * 256;
      int kr = c >> 3, kc = (c & 7) << 3;
      short8 kv = *(const short8*)(Kb + (size_t)(kt + kr) * HDq + kc);
      *(short8*)(&Ksm[kr * KSTR + kc]) = kv;
    }
    {
      short8 v0 = *(const short8*)(Vb + (size_t)(kt + vr2) * HDq + vc);
      short8 v1 = *(const short8*)(Vb + (size_t)(kt + vr2 + 1) * HDq + vc);
#pragma unroll
      for (int j = 0; j < 8; j++) {
        uint32_t pk = (uint32_t)(unsigned short)v0[j] | ((uint32_t)(unsigned short)v1[j] << 16);
        *(uint32_t*)(&Vsm[(vc + j) * VSTR + vr2]) = pk;
      }
    }
    __syncthreads();

    // S^T = K @ Q^T: sf[rb][cb] holds S[q=l16][key=cb*16+quad*4+r]
    float4v sf[2][4];
#pragma unroll
    for (int rb = 0; rb < 2; rb++)
#pragma unroll
      for (int cb = 0; cb < 4; cb++) sf[rb][cb] = zero;
#pragma unroll
    for (int cb = 0; cb < 4; cb++) {
#pragma unroll
      for (int ks = 0; ks < 2; ks++) {
        short8 kf = *(const short8*)(&Ksm[(cb * 16 + l16) * KSTR + ks * 32 + quad * 8]);
#pragma unroll
        for (int rb = 0; rb < 2; rb++)
          sf[rb][cb] = __builtin_amdgcn_mfma_f32_16x16x32_bf16(kf, qf[rb][ks], sf[rb][cb], 0, 0, 0);
      }
    }

    // P = exp(S/8) packed in-register into K=32 A-frags: pf[rb][p] covers keys
    // p*32 + quad*4 + {0..3} (j<4, from subtile cb=2p) and +16 (j>=4, cb=2p+1).
    short8 pf[2][2];
#pragma unroll
    for (int rb = 0; rb < 2; rb++)
#pragma unroll
      for (int cb = 0; cb < 4; cb++)
#pragma unroll
        for (int r = 0; r < 4; r++) {
          float p = __expf(sf[rb][cb][r] * 0.125f);
          lsum[rb] += p;
          pf[rb][cb >> 1][(cb & 1) * 4 + r] = (short)f2bf(p);
        }

    // O += P @ V  (vf: B[n=hd][k] from Vsm[hd][key], two b64 per frag)
#pragma unroll
    for (int p = 0; p < 2; p++) {
#pragma unroll
      for (int hb = 0; hb < 4; hb++) {
        short4v vlo = *(const short4v*)(&Vsm[(hb * 16 + l16) * VSTR + p * 32 + quad * 4]);
        short4v vhi = *(const short4v*)(&Vsm[(hb * 16 + l16) * VSTR + p * 32 + 16 + quad * 4]);
        short8 vf;
#pragma unroll
        for (int j = 0; j < 4; j++) { vf[j] = vlo[j]; vf[j + 4] = vhi[j]; }
#pragma unroll
        for (int rb = 0; rb < 2; rb++)
          of[rb][hb] = __builtin_amdgcn_mfma_f32_16x16x32_bf16(pf[rb][p], vf, of[rb][hb], 0, 0, 0);
      }
    }
    __syncthreads();
  }

  // denom: lane holds partial for q=l16; sum the 4 quad-copies, then fetch the
  // denom for q=quad*4+r (the C/D row this lane writes) via bpermute.
  float dinv[2][4];
#pragma unroll
  for (int rb = 0; rb < 2; rb++) {
    float l = lsum[rb];
    l += __shfl_xor(l, 16, 64);
    l += __shfl_xor(l, 32, 64);
#pragma unroll
    for (int r = 0; r < 4; r++)
      dinv[rb][r] = 1.0f / __shfl(l, quad * 4 + r, 64);
  }

  const int b = bh >> 4, h = bh & 15;
#pragma unroll
  for (int rb = 0; rb < 2; rb++)
#pragma unroll
    for (int hb = 0; hb < 4; hb++)
#pragma unroll
      for (int r = 0; r < 4; r++) {
        int srow = q0 + wave * 32 + rb * 16 + quad * 4 + r;
        int d = h * 64 + hb * 16 + l16;
        ctx[(size_t)(b * Sq + srow) * Dq + d] = f2bf(of[rb][hb][r] * dinv[rb][r]);
      }
}

extern "C" void kernel_launch(void* const* d_in, const int* in_sizes, int n_in,
                              void* d_out, int out_size, void* d_ws, size_t ws_size,
                              hipStream_t stream) {
  (void)in_sizes; (void)n_in; (void)out_size; (void)ws_size;
  const float* x  = (const float*)d_in[0];
  const float* wq = (const float*)d_in[1];
  const float* wk = (const float*)d_in[2];
  const float* wv = (const float*)d_in[3];
  const float* wo = (const float*)d_in[4];
  const float* bo = (const float*)d_in[5];
  float* out = (float*)d_out;

  char* ws = (char*)d_ws;
  const size_t MB = 1u << 20;
  unsigned short* xb  = (unsigned short*)(ws + 0 * MB);   // 8 MB  (4096x1024 bf16)
  unsigned short* wqb = (unsigned short*)(ws + 8 * MB);   // 2 MB (wq/wk/wv/wo contiguous)
  unsigned short* wkb = (unsigned short*)(ws + 10 * MB);
  unsigned short* wvb = (unsigned short*)(ws + 12 * MB);
  unsigned short* wob = (unsigned short*)(ws + 14 * MB);
  unsigned short* qb  = (unsigned short*)(ws + 16 * MB);  // 8 MB  (B,H,S,HD)
  unsigned short* kb  = (unsigned short*)(ws + 24 * MB);  // 8 MB
  unsigned short* vb  = (unsigned short*)(ws + 32 * MB);  // 8 MB
  unsigned short* cxb = (unsigned short*)(ws + 40 * MB);  // 8 MB  (B,S,D)

  cvt_kernel<<<4096, 256, 0, stream>>>(x, xb, (Bq * Sq * Dq) / 4);
  cvtw_kernel<<<dim3(1024, 4), 256, 0, stream>>>(wq, wk, wv, wo, wqb);

  gemm_bt_kernel<false><<<dim3(32, 8, 3), 256, 0, stream>>>(
      xb, wqb, wkb, wvb, qb, kb, vb, nullptr, nullptr);
  attn_kernel<<<dim3(16, 32), 256, 0, stream>>>(qb, kb, vb, cxb);
  gemm_bt_kernel<true><<<dim3(32, 8, 1), 256, 0, stream>>>(
      cxb, wob, wob, wob, nullptr, nullptr, nullptr, out, bo);
}

// Round 5
// 190.522 us; speedup vs baseline: 1.2664x; 1.1163x over previous
//
#include <hip/hip_runtime.h>
#include <hip/hip_bf16.h>
#include <stdint.h>

typedef __attribute__((ext_vector_type(8))) short short8;
typedef __attribute__((ext_vector_type(4))) float float4v;
typedef __attribute__((ext_vector_type(4))) unsigned short ushort4v;

#define Bq 2
#define Sq 2048
#define Dq 1024
#define Hq 16
#define HDq 64

__device__ __forceinline__ unsigned short f2bf(float f) {
  union { float f; uint32_t u; } v; v.f = f;
  uint32_t r = (v.u + 0x7FFFu + ((v.u >> 16) & 1u)) >> 16;
  return (unsigned short)r;
}

// packed f32x2 -> bf16x2 (v_cvt_pk_bf16_f32 on gfx950 via hip_bf16 header)
__device__ __forceinline__ uint32_t pk2bf(float a, float b) {
  union { __hip_bfloat162 h; uint32_t u; } cv;
  cv.h = __float22bfloat162_rn(make_float2(a, b));
  return cv.u;
}

// async global->LDS, 16B per lane; LDS dest must be wave-uniform base + lane*16.
__device__ __forceinline__ void gl_lds16(const unsigned short* g, unsigned short* l) {
  __builtin_amdgcn_global_load_lds(
      (const __attribute__((address_space(1))) void*)g,
      (__attribute__((address_space(3))) void*)l, 16, 0, 0);
}

// One launch: x (blocks 0..4095) + 4 weights (blocks 4096..8191, contiguous dst).
__global__ __launch_bounds__(256) void cvt_all_kernel(
    const float* __restrict__ x,
    const float* __restrict__ w0, const float* __restrict__ w1,
    const float* __restrict__ w2, const float* __restrict__ w3,
    unsigned short* __restrict__ xb, unsigned short* __restrict__ wb) {
  const int bid = blockIdx.x;
  const float* src;
  unsigned short* dst;
  int idx;
  if (bid < 4096) {
    idx = bid * 256 + threadIdx.x;            // float4 index into x (1M total)
    src = x; dst = xb;
  } else {
    int j = (bid - 4096) * 256 + threadIdx.x; // float4 index into weights (1M total)
    int z = j >> 18;
    src = (z == 0) ? w0 : (z == 1) ? w1 : (z == 2) ? w2 : w3;
    src -= (size_t)z * 1048576;               // so src + idx*4 is right with idx=j
    idx = j; dst = wb;
    src = (z == 0) ? w0 - 0 : src;            // (no-op; keep structure simple)
    // recompute cleanly:
    src = (z == 0) ? w0 : (z == 1) ? w1 : (z == 2) ? w2 : w3;
    idx = j & 262143;
    dst = wb + (size_t)(j >> 18) * 1048576 / 1;  // shorts: 1M shorts per weight? no:
    dst = wb + (size_t)(j >> 18) * 1048576;      // each weight = 1M shorts
    float4v f = ((const float4v*)src)[idx];
    ushort4v o;
#pragma unroll
    for (int q = 0; q < 4; q++) o[q] = f2bf(f[q]);
    ((ushort4v*)dst)[idx] = o;
    return;
  }
  float4v f = ((const float4v*)src)[idx];
  ushort4v o;
#pragma unroll
  for (int q = 0; q < 4; q++) o[q] = f2bf(f[q]);
  ((ushort4v*)dst)[idx] = o;
}

// C = A(bf16 MxK) @ W^T. MTxN128 tile, BK=32, global_load_lds staging (LSTR=32,
// required by wave-uniform-base+lane*16 semantics; b128 frag reads at 64B row
// stride are bank-uniform).
template <bool OUTPROJ, int MT>
__global__ __launch_bounds__(256) void gemm_bt_kernel(
    const unsigned short* __restrict__ A,
    const unsigned short* __restrict__ W0,
    const unsigned short* __restrict__ W1,
    const unsigned short* __restrict__ W2,
    unsigned short* __restrict__ q_dst,
    unsigned short* __restrict__ k_dst,
    unsigned short* __restrict__ v_dst,
    float* __restrict__ f_dst,
    const float* __restrict__ bias) {
  constexpr int K = 1024;
  constexpr int NMB = MT / 32;  // 16-row m-blocks per wave
  const int z = blockIdx.z;
  const unsigned short* W = (z == 0) ? W0 : (z == 1) ? W1 : W2;
  unsigned short* qkv = (z == 0) ? q_dst : (z == 1) ? k_dst : v_dst;

  __shared__ unsigned short Asm[MT * 32];
  __shared__ unsigned short Bsm[128 * 32];

  const int t = threadIdx.x;
  const int wave = t >> 6, lane = t & 63;
  const int quad = lane >> 4, l16 = lane & 15;
  const int wy = wave >> 1, wx = wave & 1;
  const int row0 = blockIdx.x * MT;
  const int col0 = blockIdx.y * 128;

  float4v zero = {0.f, 0.f, 0.f, 0.f};
  float4v acc[NMB][4];
#pragma unroll
  for (int i = 0; i < NMB; i++)
#pragma unroll
    for (int j = 0; j < 4; j++) acc[i][j] = zero;

  const int sr = t >> 2;
  const int sc = (t & 3) << 3;
  const unsigned short* ga = A + (size_t)(row0 + sr) * K + sc;
  const unsigned short* gb = W + (size_t)(col0 + sr) * K + sc;

  for (int k0 = 0; k0 < K; k0 += 32) {
    gl_lds16(ga + k0, &Asm[t * 8]);
    if constexpr (MT == 128) gl_lds16(ga + (size_t)64 * K + k0, &Asm[2048 + t * 8]);
    gl_lds16(gb + k0, &Bsm[t * 8]);
    gl_lds16(gb + (size_t)64 * K + k0, &Bsm[2048 + t * 8]);
    __syncthreads();
    short8 af[NMB], bf[4];
#pragma unroll
    for (int mb = 0; mb < NMB; mb++)
      af[mb] = *(const short8*)(&Asm[(wy * (MT / 2) + mb * 16 + l16) * 32 + quad * 8]);
#pragma unroll
    for (int nb = 0; nb < 4; nb++)
      bf[nb] = *(const short8*)(&Bsm[(wx * 64 + nb * 16 + l16) * 32 + quad * 8]);
#pragma unroll
    for (int mb = 0; mb < NMB; mb++)
#pragma unroll
      for (int nb = 0; nb < 4; nb++)
        acc[mb][nb] = __builtin_amdgcn_mfma_f32_16x16x32_bf16(af[mb], bf[nb], acc[mb][nb], 0, 0, 0);
    __syncthreads();
  }

#pragma unroll
  for (int mb = 0; mb < NMB; mb++) {
#pragma unroll
    for (int nb = 0; nb < 4; nb++) {
#pragma unroll
      for (int r = 0; r < 4; r++) {
        int row = row0 + wy * (MT / 2) + mb * 16 + quad * 4 + r;  // token index
        int o = col0 + wx * 64 + nb * 16 + l16;                   // output feature
        float val = acc[mb][nb][r];
        if (OUTPROJ) {
          f_dst[(size_t)row * 1024 + o] = val + bias[o];
        } else {
          int b = row >> 11, s = row & 2047;
          int h = o >> 6, hd = o & 63;
          qkv[(size_t)((b * Hq + h) * Sq + s) * HDq + hd] = f2bf(val);
        }
      }
    }
  }
}

// Flash attention, S^T trick (P stays in registers), 128-key tiles, sigma-permuted
// V so PV B-frags are single b128 reads, global->reg prefetch of next tile.
// 4 waves x 32q = 128 q/block; grid 16x32 = 512 (2 blocks/CU — grid-limited).
__global__ __launch_bounds__(256) void attn_kernel(
    const unsigned short* __restrict__ Q,
    const unsigned short* __restrict__ Kg,
    const unsigned short* __restrict__ Vg,
    unsigned short* __restrict__ ctx) {
  constexpr int KSTR = 68;   // Ksm stride (shorts)
  constexpr int VSTR = 136;  // Vsm stride (shorts): 128 keys + 8 pad
  const int bh = blockIdx.y;
  const int q0 = blockIdx.x * 128;
  const int t = threadIdx.x;
  const int wave = t >> 6, lane = t & 63;
  const int quad = lane >> 4, l16 = lane & 15;

  __shared__ unsigned short Ksm[128 * KSTR];  // [key][hd]
  __shared__ unsigned short Vsm[64 * VSTR];   // [hd][sigma(key)]

  const unsigned short* Qb = Q + (size_t)bh * Sq * HDq;
  const unsigned short* Kb = Kg + (size_t)bh * Sq * HDq;
  const unsigned short* Vb = Vg + (size_t)bh * Sq * HDq;

  short8 qf[2][2];  // [rb][ks]  A-frags of Q (32 q-rows per wave)
#pragma unroll
  for (int rb = 0; rb < 2; rb++)
#pragma unroll
    for (int ks = 0; ks < 2; ks++)
      qf[rb][ks] = *(const short8*)(Qb + (size_t)(q0 + wave * 32 + rb * 16 + l16) * HDq + ks * 32 + quad * 8);

  float4v zero = {0.f, 0.f, 0.f, 0.f};
  float4v of[2][4];
  float lsum[2] = {0.f, 0.f};
#pragma unroll
  for (int rb = 0; rb < 2; rb++)
#pragma unroll
    for (int hb = 0; hb < 4; hb++) of[rb][hb] = zero;

  // K staging geometry: pass i: row kr=(t>>3)+i*32, col kc=(t&7)*8
  const int kr0 = t >> 3, kc = (t & 7) << 3;
  // V staging geometry: pass i: key-pair vr2=(t&63)*2, cols vc8=((t>>6)+i*4)*8
  const int vr2 = (t & 63) * 2;
  const int vc8 = (t >> 6) << 3;  // + i*32
  // sigma(vr2): p*32 + quad*8 + s*4 + r  (key = p*32 + 16s + quad*4 + r)
  const int sig = (vr2 & ~31) + (((vr2 >> 2) & 3) << 3) + (((vr2 >> 4) & 1) << 2) + (vr2 & 3);

  short8 kpr[4], vpr0[2], vpr1[2];
  // prefetch tile 0
#pragma unroll
  for (int i = 0; i < 4; i++)
    kpr[i] = *(const short8*)(Kb + (size_t)(kr0 + i * 32) * HDq + kc);
#pragma unroll
  for (int i = 0; i < 2; i++) {
    vpr0[i] = *(const short8*)(Vb + (size_t)vr2 * HDq + vc8 + i * 32);
    vpr1[i] = *(const short8*)(Vb + (size_t)(vr2 + 1) * HDq + vc8 + i * 32);
  }

  for (int kt = 0; kt < Sq; kt += 128) {
    // write prefetched regs to LDS
#pragma unroll
    for (int i = 0; i < 4; i++)
      *(short8*)(&Ksm[(kr0 + i * 32) * KSTR + kc]) = kpr[i];
#pragma unroll
    for (int i = 0; i < 2; i++)
#pragma unroll
      for (int j = 0; j < 8; j++) {
        uint32_t pk = (uint32_t)(unsigned short)vpr0[i][j] |
                      ((uint32_t)(unsigned short)vpr1[i][j] << 16);
        *(uint32_t*)(&Vsm[(vc8 + i * 32 + j) * VSTR + sig]) = pk;
      }
    __syncthreads();

    // issue global loads for next tile (latency hidden under compute)
    if (kt + 128 < Sq) {
      const unsigned short* Kn = Kb + (size_t)(kt + 128) * HDq;
      const unsigned short* Vn = Vb + (size_t)(kt + 128) * HDq;
#pragma unroll
      for (int i = 0; i < 4; i++)
        kpr[i] = *(const short8*)(Kn + (size_t)(kr0 + i * 32) * HDq + kc);
#pragma unroll
      for (int i = 0; i < 2; i++) {
        vpr0[i] = *(const short8*)(Vn + (size_t)vr2 * HDq + vc8 + i * 32);
        vpr1[i] = *(const short8*)(Vn + (size_t)(vr2 + 1) * HDq + vc8 + i * 32);
      }
    }

    // 4 chunks of 32 keys: QK^T (S^T layout) -> exp -> packed P A-frag -> PV
#pragma unroll
    for (int p = 0; p < 4; p++) {
      float4v sf[2][2];
#pragma unroll
      for (int rb = 0; rb < 2; rb++)
#pragma unroll
        for (int s = 0; s < 2; s++) sf[rb][s] = zero;
#pragma unroll
      for (int s = 0; s < 2; s++)
#pragma unroll
        for (int ks = 0; ks < 2; ks++) {
          short8 kf = *(const short8*)(&Ksm[(p * 32 + s * 16 + l16) * KSTR + ks * 32 + quad * 8]);
#pragma unroll
          for (int rb = 0; rb < 2; rb++)
            sf[rb][s] = __builtin_amdgcn_mfma_f32_16x16x32_bf16(kf, qf[rb][ks], sf[rb][s], 0, 0, 0);
        }
      short8 pf[2];
#pragma unroll
      for (int rb = 0; rb < 2; rb++) {
        union { uint32_t u[4]; short8 v; } pw;
#pragma unroll
        for (int s = 0; s < 2; s++)
#pragma unroll
          for (int rp = 0; rp < 2; rp++) {
            float pa = __expf(sf[rb][s][rp * 2] * 0.125f);
            float pb = __expf(sf[rb][s][rp * 2 + 1] * 0.125f);
            lsum[rb] += pa + pb;
            pw.u[s * 2 + rp] = pk2bf(pa, pb);
          }
        pf[rb] = pw.v;
      }
#pragma unroll
      for (int hb = 0; hb < 4; hb++) {
        short8 vf = *(const short8*)(&Vsm[(hb * 16 + l16) * VSTR + p * 32 + quad * 8]);
#pragma unroll
        for (int rb = 0; rb < 2; rb++)
          of[rb][hb] = __builtin_amdgcn_mfma_f32_16x16x32_bf16(pf[rb], vf, of[rb][hb], 0, 0, 0);
      }
    }
    __syncthreads();
  }

  // denominators: lane's lsum covers q=l16 partial; sum quads, fetch per C/D row.
  float dinv[2][4];
#pragma unroll
  for (int rb = 0; rb < 2; rb++) {
    float l = lsum[rb];
    l += __shfl_xor(l, 16, 64);
    l += __shfl_xor(l, 32, 64);
#pragma unroll
    for (int r = 0; r < 4; r++)
      dinv[rb][r] = 1.0f / __shfl(l, quad * 4 + r, 64);
  }

  const int b = bh >> 4, h = bh & 15;
#pragma unroll
  for (int rb = 0; rb < 2; rb++)
#pragma unroll
    for (int hb = 0; hb < 4; hb++)
#pragma unroll
      for (int r = 0; r < 4; r++) {
        int srow = q0 + wave * 32 + rb * 16 + quad * 4 + r;
        int d = h * 64 + hb * 16 + l16;
        ctx[(size_t)(b * Sq + srow) * Dq + d] = f2bf(of[rb][hb][r] * dinv[rb][r]);
      }
}

extern "C" void kernel_launch(void* const* d_in, const int* in_sizes, int n_in,
                              void* d_out, int out_size, void* d_ws, size_t ws_size,
                              hipStream_t stream) {
  (void)in_sizes; (void)n_in; (void)out_size; (void)ws_size;
  const float* x  = (const float*)d_in[0];
  const float* wq = (const float*)d_in[1];
  const float* wk = (const float*)d_in[2];
  const float* wv = (const float*)d_in[3];
  const float* wo = (const float*)d_in[4];
  const float* bo = (const float*)d_in[5];
  float* out = (float*)d_out;

  char* ws = (char*)d_ws;
  const size_t MB = 1u << 20;
  unsigned short* xb  = (unsigned short*)(ws + 0 * MB);   // 8 MB  (4096x1024 bf16)
  unsigned short* wqb = (unsigned short*)(ws + 8 * MB);   // 2 MB each, contiguous
  unsigned short* wkb = (unsigned short*)(ws + 10 * MB);
  unsigned short* wvb = (unsigned short*)(ws + 12 * MB);
  unsigned short* wob = (unsigned short*)(ws + 14 * MB);
  unsigned short* qb  = (unsigned short*)(ws + 16 * MB);  // 8 MB  (B,H,S,HD)
  unsigned short* kb  = (unsigned short*)(ws + 24 * MB);  // 8 MB
  unsigned short* vb  = (unsigned short*)(ws + 32 * MB);  // 8 MB
  unsigned short* cxb = (unsigned short*)(ws + 40 * MB);  // 8 MB  (B,S,D)

  cvt_all_kernel<<<8192, 256, 0, stream>>>(x, wq, wk, wv, wo, xb, wqb);

  gemm_bt_kernel<false, 128><<<dim3(32, 8, 3), 256, 0, stream>>>(
      xb, wqb, wkb, wvb, qb, kb, vb, nullptr, nullptr);
  attn_kernel<<<dim3(16, 32), 256, 0, stream>>>(qb, kb, vb, cxb);
  gemm_bt_kernel<true, 64><<<dim3(64, 8, 1), 256, 0, stream>>>(
      cxb, wob, wob, wob, nullptr, nullptr, nullptr, out, bo);
}

// Round 7
// 187.043 us; speedup vs baseline: 1.2900x; 1.0186x over previous
//
#include <hip/hip_runtime.h>
#include <hip/hip_bf16.h>
#include <stdint.h>

typedef __attribute__((ext_vector_type(8))) short short8;
typedef __attribute__((ext_vector_type(4))) float float4v;
typedef __attribute__((ext_vector_type(4))) unsigned short ushort4v;

#define Bq 2
#define Sq 2048
#define Dq 1024
#define Hq 16
#define HDq 64

// 0.125 * log2(e): folded into Q at the QKV-GEMM epilogue so attention can use
// exp2 directly with no per-score scaling.
#define QSCALE 0.18033688011112042f

__device__ __forceinline__ unsigned short f2bf(float f) {
  union { float f; uint32_t u; } v; v.f = f;
  uint32_t r = (v.u + 0x7FFFu + ((v.u >> 16) & 1u)) >> 16;
  return (unsigned short)r;
}

// packed f32x2 -> bf16x2 (v_cvt_pk_bf16_f32 on gfx950)
__device__ __forceinline__ uint32_t pk2bf(float a, float b) {
  union { __hip_bfloat162 h; uint32_t u; } cv;
  cv.h = __float22bfloat162_rn(make_float2(a, b));
  return cv.u;
}

// async global->LDS, 16B per lane; LDS dest is wave-uniform base + lane*16.
__device__ __forceinline__ void gl_lds16(const unsigned short* g, unsigned short* l) {
  __builtin_amdgcn_global_load_lds(
      (const __attribute__((address_space(1))) void*)g,
      (__attribute__((address_space(3))) void*)l, 16, 0, 0);
}

// One launch: x (blocks 0..4095) + 4 weights (blocks 4096..8191, contiguous dst).
__global__ __launch_bounds__(256) void cvt_all_kernel(
    const float* __restrict__ x,
    const float* __restrict__ w0, const float* __restrict__ w1,
    const float* __restrict__ w2, const float* __restrict__ w3,
    unsigned short* __restrict__ xb, unsigned short* __restrict__ wb) {
  const int bid = blockIdx.x;
  const float* src;
  unsigned short* dst;
  int idx;
  if (bid < 4096) {
    src = x; dst = xb;
    idx = bid * 256 + threadIdx.x;
  } else {
    int j = (bid - 4096) * 256 + threadIdx.x;  // float4 index across 4 weights
    int z = j >> 18;                           // 262144 float4 per weight
    src = (z == 0) ? w0 : (z == 1) ? w1 : (z == 2) ? w2 : w3;
    dst = wb + (size_t)z * 1048576;            // 1M shorts per weight
    idx = j & 262143;
  }
  float4v f = ((const float4v*)src)[idx];
  ushort4v o;
#pragma unroll
  for (int q = 0; q < 4; q++) o[q] = f2bf(f[q]);
  ((ushort4v*)dst)[idx] = o;
}

// C = A(bf16 MxK) @ W^T. MT x 128 tile, BK=64, global_load_lds staging.
// LDS layout XOR-swizzled on 16B granules (phys_g = g ^ (row&7)): at 128B row
// stride unswizzled b128 frag reads are 16-way bank conflicts; swizzled 2-way
// (free). Staging side absorbs the swizzle in the precomputed global address.
// QKV epilogue scales Q (z==0) by QSCALE in fp32 before bf16 rounding.
template <bool OUTPROJ, int MT>
__global__ __launch_bounds__(256) void gemm_bt_kernel(
    const unsigned short* __restrict__ A,
    const unsigned short* __restrict__ W0,
    const unsigned short* __restrict__ W1,
    const unsigned short* __restrict__ W2,
    unsigned short* __restrict__ q_dst,
    unsigned short* __restrict__ k_dst,
    unsigned short* __restrict__ v_dst,
    float* __restrict__ f_dst,
    const float* __restrict__ bias) {
  constexpr int K = 1024;
  constexpr int NMB = MT / 32;    // 16-row m-blocks per wave
  constexpr int APASS = MT / 32;  // staging passes for A (32 rows each)
  const int z = blockIdx.z;
  const unsigned short* W = (z == 0) ? W0 : (z == 1) ? W1 : W2;
  unsigned short* qkv = (z == 0) ? q_dst : (z == 1) ? k_dst : v_dst;

  __shared__ unsigned short Asm[MT * 64];
  __shared__ unsigned short Bsm[128 * 64];

  const int t = threadIdx.x;
  const int wave = t >> 6, lane = t & 63;
  const int quad = lane >> 4, l16 = lane & 15;
  const int wy = wave >> 1, wx = wave & 1;
  const int row0 = blockIdx.x * MT;
  const int col0 = blockIdx.y * 128;

  float4v zero = {0.f, 0.f, 0.f, 0.f};
  float4v acc[NMB][4];
#pragma unroll
  for (int i = 0; i < NMB; i++)
#pragma unroll
    for (int j = 0; j < 4; j++) acc[i][j] = zero;

  // staging geometry: pass i covers rows i*32..i*32+31; thread t -> row i*32+(t>>3),
  // phys granule t&7, logical granule (t&7)^((t>>3)&7). LDS slot = i*2048 + t*8.
  const int srow = t >> 3;
  const int sgl = ((t & 7) ^ (srow & 7)) << 3;  // logical col in shorts
  const unsigned short* gA[APASS];
  const unsigned short* gB[4];
#pragma unroll
  for (int i = 0; i < APASS; i++)
    gA[i] = A + (size_t)(row0 + i * 32 + srow) * K + sgl;
#pragma unroll
  for (int i = 0; i < 4; i++)
    gB[i] = W + (size_t)(col0 + i * 32 + srow) * K + sgl;

  const int swl = (l16 & 7);  // frag-read swizzle key

  for (int k0 = 0; k0 < K; k0 += 64) {
#pragma unroll
    for (int i = 0; i < APASS; i++) gl_lds16(gA[i] + k0, &Asm[i * 2048 + t * 8]);
#pragma unroll
    for (int i = 0; i < 4; i++) gl_lds16(gB[i] + k0, &Bsm[i * 2048 + t * 8]);
    __syncthreads();
    short8 af[NMB][2], bf[4][2];
#pragma unroll
    for (int ks = 0; ks < 2; ks++) {
#pragma unroll
      for (int mb = 0; mb < NMB; mb++) {
        int row = wy * (MT / 2) + mb * 16 + l16;
        int pg = (ks * 4 + quad) ^ swl;
        af[mb][ks] = *(const short8*)(&Asm[row * 64 + pg * 8]);
      }
#pragma unroll
      for (int nb = 0; nb < 4; nb++) {
        int row = wx * 64 + nb * 16 + l16;
        int pg = (ks * 4 + quad) ^ swl;
        bf[nb][ks] = *(const short8*)(&Bsm[row * 64 + pg * 8]);
      }
    }
#pragma unroll
    for (int ks = 0; ks < 2; ks++)
#pragma unroll
      for (int mb = 0; mb < NMB; mb++)
#pragma unroll
        for (int nb = 0; nb < 4; nb++)
          acc[mb][nb] = __builtin_amdgcn_mfma_f32_16x16x32_bf16(af[mb][ks], bf[nb][ks], acc[mb][nb], 0, 0, 0);
    __syncthreads();
  }

  const float qsc = (!OUTPROJ && z == 0) ? QSCALE : 1.0f;
#pragma unroll
  for (int mb = 0; mb < NMB; mb++) {
#pragma unroll
    for (int nb = 0; nb < 4; nb++) {
#pragma unroll
      for (int r = 0; r < 4; r++) {
        int row = row0 + wy * (MT / 2) + mb * 16 + quad * 4 + r;  // token index
        int o = col0 + wx * 64 + nb * 16 + l16;                   // output feature
        float val = acc[mb][nb][r];
        if (OUTPROJ) {
          f_dst[(size_t)row * 1024 + o] = val + bias[o];
        } else {
          int b = row >> 11, s = row & 2047;
          int h = o >> 6, hd = o & 63;
          qkv[(size_t)((b * Hq + h) * Sq + s) * HDq + hd] = f2bf(val * qsc);
        }
      }
    }
  }
}

// Flash attention: S^T trick (P in registers), 128-key tiles, sigma-permuted V
// (PV B-frags are single b128), global->reg prefetch, exp2 (scale pre-folded
// into Q), denominators via ones-column MFMA (C-layout aligned with of -> no
// shuffle reduce). 4 waves x 32q = 128 q/block; grid 16x32 = 512 (2 blocks/CU).
__global__ __launch_bounds__(256) void attn_kernel(
    const unsigned short* __restrict__ Q,
    const unsigned short* __restrict__ Kg,
    const unsigned short* __restrict__ Vg,
    unsigned short* __restrict__ ctx) {
  constexpr int KSTR = 68;   // Ksm stride (shorts)
  constexpr int VSTR = 136;  // Vsm stride (shorts)
  const int bh = blockIdx.y;
  const int q0 = blockIdx.x * 128;
  const int t = threadIdx.x;
  const int wave = t >> 6, lane = t & 63;
  const int quad = lane >> 4, l16 = lane & 15;

  __shared__ unsigned short Ksm[128 * KSTR];  // [key][hd]
  __shared__ unsigned short Vsm[64 * VSTR];   // [hd][sigma(key)]

  const unsigned short* Qb = Q + (size_t)bh * Sq * HDq;
  const unsigned short* Kb = Kg + (size_t)bh * Sq * HDq;
  const unsigned short* Vb = Vg + (size_t)bh * Sq * HDq;

  short8 qf[2][2];  // [rb][ks]
#pragma unroll
  for (int rb = 0; rb < 2; rb++)
#pragma unroll
    for (int ks = 0; ks < 2; ks++)
      qf[rb][ks] = *(const short8*)(Qb + (size_t)(q0 + wave * 32 + rb * 16 + l16) * HDq + ks * 32 + quad * 8);

  short8 ones;
#pragma unroll
  for (int j = 0; j < 8; j++) ones[j] = (short)0x3F80;  // bf16 1.0

  float4v zero = {0.f, 0.f, 0.f, 0.f};
  float4v of[2][4];
  float4v dsum[2] = {zero, zero};
#pragma unroll
  for (int rb = 0; rb < 2; rb++)
#pragma unroll
    for (int hb = 0; hb < 4; hb++) of[rb][hb] = zero;

  const int kr0 = t >> 3, kc = (t & 7) << 3;
  const int vr2 = (t & 63) * 2;
  const int vc8 = (t >> 6) << 3;
  const int sig = (vr2 & ~31) + (((vr2 >> 2) & 3) << 3) + (((vr2 >> 4) & 1) << 2) + (vr2 & 3);

  short8 kpr[4], vpr0[2], vpr1[2];
#pragma unroll
  for (int i = 0; i < 4; i++)
    kpr[i] = *(const short8*)(Kb + (size_t)(kr0 + i * 32) * HDq + kc);
#pragma unroll
  for (int i = 0; i < 2; i++) {
    vpr0[i] = *(const short8*)(Vb + (size_t)vr2 * HDq + vc8 + i * 32);
    vpr1[i] = *(const short8*)(Vb + (size_t)(vr2 + 1) * HDq + vc8 + i * 32);
  }

  for (int kt = 0; kt < Sq; kt += 128) {
#pragma unroll
    for (int i = 0; i < 4; i++)
      *(short8*)(&Ksm[(kr0 + i * 32) * KSTR + kc]) = kpr[i];
#pragma unroll
    for (int i = 0; i < 2; i++)
#pragma unroll
      for (int j = 0; j < 8; j++) {
        uint32_t pk = (uint32_t)(unsigned short)vpr0[i][j] |
                      ((uint32_t)(unsigned short)vpr1[i][j] << 16);
        *(uint32_t*)(&Vsm[(vc8 + i * 32 + j) * VSTR + sig]) = pk;
      }
    __syncthreads();

    if (kt + 128 < Sq) {
      const unsigned short* Kn = Kb + (size_t)(kt + 128) * HDq;
      const unsigned short* Vn = Vb + (size_t)(kt + 128) * HDq;
#pragma unroll
      for (int i = 0; i < 4; i++)
        kpr[i] = *(const short8*)(Kn + (size_t)(kr0 + i * 32) * HDq + kc);
#pragma unroll
      for (int i = 0; i < 2; i++) {
        vpr0[i] = *(const short8*)(Vn + (size_t)vr2 * HDq + vc8 + i * 32);
        vpr1[i] = *(const short8*)(Vn + (size_t)(vr2 + 1) * HDq + vc8 + i * 32);
      }
    }

#pragma unroll
    for (int p = 0; p < 4; p++) {
      float4v sf[2][2];
#pragma unroll
      for (int rb = 0; rb < 2; rb++)
#pragma unroll
        for (int s = 0; s < 2; s++) sf[rb][s] = zero;
#pragma unroll
      for (int s = 0; s < 2; s++)
#pragma unroll
        for (int ks = 0; ks < 2; ks++) {
          short8 kf = *(const short8*)(&Ksm[(p * 32 + s * 16 + l16) * KSTR + ks * 32 + quad * 8]);
#pragma unroll
          for (int rb = 0; rb < 2; rb++)
            sf[rb][s] = __builtin_amdgcn_mfma_f32_16x16x32_bf16(kf, qf[rb][ks], sf[rb][s], 0, 0, 0);
        }
      short8 pf[2];
#pragma unroll
      for (int rb = 0; rb < 2; rb++) {
        union { uint32_t u[4]; short8 v; } pw;
#pragma unroll
        for (int s = 0; s < 2; s++)
#pragma unroll
          for (int rp = 0; rp < 2; rp++) {
            float pa = __builtin_amdgcn_exp2f(sf[rb][s][rp * 2]);
            float pb = __builtin_amdgcn_exp2f(sf[rb][s][rp * 2 + 1]);
            pw.u[s * 2 + rp] = pk2bf(pa, pb);
          }
        pf[rb] = pw.v;
      }
#pragma unroll
      for (int rb = 0; rb < 2; rb++)
        dsum[rb] = __builtin_amdgcn_mfma_f32_16x16x32_bf16(pf[rb], ones, dsum[rb], 0, 0, 0);
#pragma unroll
      for (int hb = 0; hb < 4; hb++) {
        short8 vf = *(const short8*)(&Vsm[(hb * 16 + l16) * VSTR + p * 32 + quad * 8]);
#pragma unroll
        for (int rb = 0; rb < 2; rb++)
          of[rb][hb] = __builtin_amdgcn_mfma_f32_16x16x32_bf16(pf[rb], vf, of[rb][hb], 0, 0, 0);
      }
    }
    __syncthreads();
  }

  const int b = bh >> 4, h = bh & 15;
#pragma unroll
  for (int rb = 0; rb < 2; rb++) {
    float4v dinv;
#pragma unroll
    for (int r = 0; r < 4; r++) dinv[r] = 1.0f / dsum[rb][r];
#pragma unroll
    for (int hb = 0; hb < 4; hb++)
#pragma unroll
      for (int r = 0; r < 4; r++) {
        int srow = q0 + wave * 32 + rb * 16 + quad * 4 + r;
        int d = h * 64 + hb * 16 + l16;
        ctx[(size_t)(b * Sq + srow) * Dq + d] = f2bf(of[rb][hb][r] * dinv[r]);
      }
  }
}

extern "C" void kernel_launch(void* const* d_in, const int* in_sizes, int n_in,
                              void* d_out, int out_size, void* d_ws, size_t ws_size,
                              hipStream_t stream) {
  (void)in_sizes; (void)n_in; (void)out_size; (void)ws_size;
  const float* x  = (const float*)d_in[0];
  const float* wq = (const float*)d_in[1];
  const float* wk = (const float*)d_in[2];
  const float* wv = (const float*)d_in[3];
  const float* wo = (const float*)d_in[4];
  const float* bo = (const float*)d_in[5];
  float* out = (float*)d_out;

  char* ws = (char*)d_ws;
  const size_t MB = 1u << 20;
  unsigned short* xb  = (unsigned short*)(ws + 0 * MB);   // 8 MB  (4096x1024 bf16)
  unsigned short* wqb = (unsigned short*)(ws + 8 * MB);   // 2 MB each, contiguous
  unsigned short* wkb = (unsigned short*)(ws + 10 * MB);
  unsigned short* wvb = (unsigned short*)(ws + 12 * MB);
  unsigned short* wob = (unsigned short*)(ws + 14 * MB);
  unsigned short* qb  = (unsigned short*)(ws + 16 * MB);  // 8 MB  (B,H,S,HD), pre-scaled
  unsigned short* kb  = (unsigned short*)(ws + 24 * MB);  // 8 MB
  unsigned short* vb  = (unsigned short*)(ws + 32 * MB);  // 8 MB
  unsigned short* cxb = (unsigned short*)(ws + 40 * MB);  // 8 MB  (B,S,D)

  cvt_all_kernel<<<8192, 256, 0, stream>>>(x, wq, wk, wv, wo, xb, wqb);

  gemm_bt_kernel<false, 128><<<dim3(32, 8, 3), 256, 0, stream>>>(
      xb, wqb, wkb, wvb, qb, kb, vb, nullptr, nullptr);
  attn_kernel<<<dim3(16, 32), 256, 0, stream>>>(qb, kb, vb, cxb);
  gemm_bt_kernel<true, 64><<<dim3(64, 8, 1), 256, 0, stream>>>(
      cxb, wob, wob, wob, nullptr, nullptr, nullptr, out, bo);
}